// Round 5
// baseline (2648.738 us; speedup 1.0000x reference)
//
#include <hip/hip_runtime.h>
#include <hip/hip_cooperative_groups.h>

namespace cg = cooperative_groups;

#define T_STEPS 24
#define BB 64
#define I_DIM 128
#define HH 256
#define RR 64
#define HR 320   // H + R

// ---------------- init: per-(i,j) constants ----------------
__global__ __launch_bounds__(256) void k_init_const(
    const float* __restrict__ alpha, const float* __restrict__ tau_U,
    const float* __restrict__ tau_E, const float* __restrict__ tau_v,
    const float* __restrict__ h2h_w,
    float* __restrict__ ra, float* __restrict__ sU, float* __restrict__ sE,
    float* __restrict__ hi, float* __restrict__ lo, float* __restrict__ sv)
{
    int idx = blockIdx.x * 256 + threadIdx.x;
    if (idx >= HH * HH) return;
    float a = alpha[idx]; a = a > 0.f ? a : 0.f;
    ra[idx] = a;
    sU[idx] = 1.f / (1.f + expf(-tau_U[idx]));
    sE[idx] = 1.f / (1.f + expf(-tau_E[idx]));
    float wv = h2h_w[idx];
    float inv = 1.f / (a + 1e-8f);
    float hi_ = 1.0f - wv; hi_ = hi_ > 0.f ? hi_ : 0.f;
    float lo_ = 1.0f + wv; lo_ = lo_ > 0.f ? lo_ : 0.f;
    hi[idx] = hi_ * inv;
    lo[idx] = -lo_ * inv;
    if (idx < HH) sv[idx] = 1.f / (1.f + expf(-tau_v[idx]));
}

// ---------------- init: Wx = LN(x @ x2h_w.T + b) for all T ----------------
__global__ __launch_bounds__(HR) void k_wx(
    const float* __restrict__ x, const float* __restrict__ w,
    const float* __restrict__ bias,
    const float* __restrict__ g, const float* __restrict__ be,
    float* __restrict__ Wx)
{
    __shared__ float xs[I_DIM];
    __shared__ float rs[5], rs2[5];
    int row = blockIdx.x;
    int p = threadIdx.x;
    if (p < I_DIM) xs[p] = x[(size_t)row * I_DIM + p];
    __syncthreads();
    const float* wr = w + (size_t)p * I_DIM;
    float acc = bias[p];
    #pragma unroll 8
    for (int k = 0; k < I_DIM; k += 4)
        acc += wr[k]*xs[k] + wr[k+1]*xs[k+1] + wr[k+2]*xs[k+2] + wr[k+3]*xs[k+3];
    float s = acc, s2 = acc * acc;
    int lane = p & 63, wv = p >> 6;
    for (int off = 32; off > 0; off >>= 1) { s += __shfl_down(s, off); s2 += __shfl_down(s2, off); }
    if (lane == 0) { rs[wv] = s; rs2[wv] = s2; }
    __syncthreads();
    float sum = 0.f, sum2 = 0.f;
    #pragma unroll
    for (int q = 0; q < 5; q++) { sum += rs[q]; sum2 += rs2[q]; }
    float mu = sum * (1.f / HR);
    float rstd = rsqrtf(sum2 * (1.f / HR) - mu * mu + 1e-5f);
    Wx[(size_t)row * HR + p] = (acc - mu) * rstd * g[p] + be[p];
}

// ---------------- init: s0 = einsum(ra*dU0, h0) ----------------
__global__ __launch_bounds__(256) void k_s0(
    const float* __restrict__ dU0, const float* __restrict__ h0,
    const float* __restrict__ ra, float* __restrict__ s_out)
{
    int r = blockIdx.x * 4 + (threadIdx.x >> 6);
    int lane = threadIdx.x & 63;
    int b = r >> 8, i = r & 255;
    float4 du = ((const float4*)dU0)[(size_t)r * 64 + lane];
    float4 rv = ((const float4*)ra)[(size_t)i * 64 + lane];
    float4 hv = ((const float4*)h0)[(size_t)b * 64 + lane];
    float acc = rv.x*du.x*hv.x + rv.y*du.y*hv.y + rv.z*du.z*hv.z + rv.w*du.w*hv.w;
    for (int off = 32; off > 0; off >>= 1) acc += __shfl_down(acc, off);
    if (lane == 0) s_out[r] = acc;
}

// ---------------- init: Wh_pre(0) = h0 @ h2h_w.T + b ----------------
__global__ __launch_bounds__(HR) void k_wh0(
    const float* __restrict__ h0, const float* __restrict__ w,
    const float* __restrict__ bias, float* __restrict__ whp)
{
    __shared__ float hs[HH];
    int b = blockIdx.x, p = threadIdx.x;
    if (p < HH) hs[p] = h0[(size_t)b * HH + p];
    __syncthreads();
    const float* wr = w + (size_t)p * HH;
    float acc = bias[p];
    #pragma unroll 8
    for (int k = 0; k < HH; k += 4)
        acc += wr[k]*hs[k] + wr[k+1]*hs[k+1] + wr[k+2]*hs[k+2] + wr[k+3]*hs[k+3];
    whp[(size_t)b * HR + p] = acc;
}

// ---------------- persistent cooperative scan kernel ----------------
// grid 512 = 64 batches x 8 row-groups (2 blocks/CU); block 256 threads.
// Each thread owns rows i0=g*32+(tid>>4) and i0+16; per row 16 dU + 16 tE
// elements in registers: j = jg*4 + 64*k + c, k=0..3, c=0..3, jg = tid&15.
__global__ __launch_bounds__(256, 2) void k_scan(
    const float* __restrict__ dU0, const float* __restrict__ tE0,
    const float* __restrict__ h0, const float* __restrict__ v0,
    const float* __restrict__ te0,
    const float* __restrict__ Wx,      // (T,B,HR)
    const float* __restrict__ h2h_w, const float* __restrict__ h2h_b,
    const float* __restrict__ lnh_g, const float* __restrict__ lnh_b,
    const float* __restrict__ sv_g,    // (H)
    const float* __restrict__ mod2h,   // (H,R)
    const float* __restrict__ ra, const float* __restrict__ sU,
    const float* __restrict__ sE, const float* __restrict__ hi,
    const float* __restrict__ lo,
    float* __restrict__ whpA, float* __restrict__ whpB,   // (B,HR) x2 parity
    float* __restrict__ sbufA, float* __restrict__ sbufB, // (B,H) x2 parity
    float* __restrict__ o_v, float* __restrict__ o_h, float* __restrict__ o_dU,
    float* __restrict__ o_te, float* __restrict__ o_tE, float* __restrict__ o_out)
{
    cg::grid_group grid = cg::this_grid();

    __shared__ __align__(16) float sh_h[2][HH];
    __shared__ __align__(16) float sh_te[2][HH];
    __shared__ float sh_v[HH];
    __shared__ __align__(16) float sh_modin[RR];
    __shared__ float sh_red[4], sh_red2[4];

    const int bk  = blockIdx.x;
    const int b   = bk >> 3;
    const int g   = bk & 7;
    const int tid = threadIdx.x;
    const int row_local = tid >> 4;
    const int jg  = tid & 15;
    const int i0  = g * 32 + row_local;
    const int wv  = tid >> 6;
    const int lane = tid & 63;

    const float svp = sv_g[tid];
    const float g0 = lnh_g[tid],  be0 = lnh_b[tid];
    float g1 = 0.f, be1 = 0.f;
    if (tid < 64) { g1 = lnh_g[HH + tid]; be1 = lnh_b[HH + tid]; }

    // persistent register state: 2 rows x (16 dU + 16 tE)
    const size_t rbase = ((size_t)(b * HH + i0)) * 64 + jg;  // float4 units
    const float4* dU0v = (const float4*)dU0;
    const float4* tE0v = (const float4*)tE0;
    float4 du[2][4], tEr[2][4];
    #pragma unroll
    for (int r = 0; r < 2; ++r) {
        const size_t rb = rbase + (size_t)r * (16 * 64);
        #pragma unroll
        for (int k = 0; k < 4; ++k) {
            du[r][k]  = dU0v[rb + k * 16];
            tEr[r][k] = tE0v[rb + k * 16];
        }
    }

    const float4* raV4 = (const float4*)ra;
    const float4* sUV4 = (const float4*)sU;
    const float4* sEV4 = (const float4*)sE;
    const float4* hiV4 = (const float4*)hi;
    const float4* loV4 = (const float4*)lo;

    sh_h[0][tid]  = h0[(size_t)b * HH + tid];
    sh_te[0][tid] = te0[(size_t)b * HH + tid];
    sh_v[tid]     = v0[(size_t)b * HH + tid];
    __syncthreads();

    #pragma unroll 1
    for (int t = 0; t < T_STEPS; t++) {
        const int cur = t & 1, nxt = cur ^ 1;
        const float* whp  = (cur == 0) ? whpA  : whpB;
        float*       whpn = (cur == 0) ? whpB  : whpA;
        const float* sbi  = (cur == 0) ? sbufA : sbufB;
        float*       sbo  = (cur == 0) ? sbufB : sbufA;

        // ---- A2: LN(Wh_pre) + v/nh/nte/modin (redundant across the 8 blocks of b)
        const float* whb = whp + (size_t)b * HR;
        float p0 = whb[tid];
        float p1 = (tid < 64) ? whb[HH + tid] : 0.f;
        float s = p0 + p1, s2 = p0 * p0 + p1 * p1;
        #pragma unroll
        for (int off = 32; off > 0; off >>= 1) { s += __shfl_down(s, off); s2 += __shfl_down(s2, off); }
        if (lane == 0) { sh_red[wv] = s; sh_red2[wv] = s2; }
        __syncthreads();
        float sum = sh_red[0] + sh_red[1] + sh_red[2] + sh_red[3];
        float sum2 = sh_red2[0] + sh_red2[1] + sh_red2[2] + sh_red2[3];
        float mu = sum * (1.f / HR);
        float rstd = rsqrtf(sum2 * (1.f / HR) - mu * mu + 1e-5f);

        const float* wx_t = Wx + ((size_t)t * BB + b) * HR;
        float wh0 = (p0 - mu) * rstd * g0 + be0;
        float dv = wx_t[tid] + wh0 + sbi[(size_t)b * HH + tid];
        float vnew = (1.f - svp) * sh_v[tid] + svp * dv;
        sh_v[tid] = vnew;
        float nh = vnew > 0.f ? vnew : 0.f;
        sh_h[nxt][tid] = nh;
        sh_te[nxt][tid] = (1.f - svp) * sh_te[cur][tid] + svp * sh_h[cur][tid];
        if (tid < 64) {
            float wh1 = (p1 - mu) * rstd * g1 + be1;
            float m = wx_t[HH + tid] + wh1;
            sh_modin[tid] = m > 0.f ? m : 0.f;
        }
        if (g == 0) o_out[((size_t)t * BB + b) * HH + tid] = nh;
        __syncthreads();

        // ---- B: per-row mod, register dU/tE update + fused einsum (2 rows)
#define COMPONENT(c, jj) { \
        float teO = sh_te[cur][jj]; float hO = sh_h[cur][jj]; float nhJ = sh_h[nxt][jj]; \
        float e = (1.f - sEV.c) * TE.c + sEV.c * (nhi * teO - ntei * hO); \
        float d = (1.f - sUV.c) * DU.c + sUV.c * modi * e; \
        d = fminf(d, hiV.c); d = fmaxf(d, loV.c); \
        TE.c = e; DU.c = d; acc += raV.c * d * nhJ; }

        #pragma unroll
        for (int r = 0; r < 2; ++r) {
            const int i = i0 + r * 16;
            float4 m4 = *(const float4*)(mod2h + (size_t)i * RR + jg * 4);
            float4 mi = *(const float4*)&sh_modin[jg * 4];
            float macc = m4.x*mi.x + m4.y*mi.y + m4.z*mi.z + m4.w*mi.w;
            macc += __shfl_down(macc, 8, 16);
            macc += __shfl_down(macc, 4, 16);
            macc += __shfl_down(macc, 2, 16);
            macc += __shfl_down(macc, 1, 16);
            const float modi = __shfl(macc, 0, 16);
            const float nhi  = sh_h[nxt][i];
            const float ntei = sh_te[nxt][i];
            float acc = 0.f;
            #pragma unroll
            for (int k = 0; k < 4; ++k) {
                const size_t ci = (size_t)i * 64 + jg + k * 16;
                const float4 raV = raV4[ci]; const float4 sUV = sUV4[ci];
                const float4 sEV = sEV4[ci]; const float4 hiV = hiV4[ci];
                const float4 loV = loV4[ci];
                float4 &DU = du[r][k];
                float4 &TE = tEr[r][k];
                const int j0 = k * 64 + jg * 4;
                COMPONENT(x, j0 + 0) COMPONENT(y, j0 + 1)
                COMPONENT(z, j0 + 2) COMPONENT(w, j0 + 3)
            }
            acc += __shfl_down(acc, 8, 16);
            acc += __shfl_down(acc, 4, 16);
            acc += __shfl_down(acc, 2, 16);
            acc += __shfl_down(acc, 1, 16);
            if (jg == 0) sbo[(size_t)b * HH + i] = acc;
        }
#undef COMPONENT

        // ---- A1: Wh_pre(t+1) = nh @ h2h_w.T + bias, 40 rows per block
        if (t != T_STEPS - 1) {
            #pragma unroll
            for (int k = 0; k < 10; k++) {
                int p = g * 40 + wv + 4 * k;
                float4 wrow = ((const float4*)(h2h_w + (size_t)p * HH))[lane];
                float4 hv = *(const float4*)&sh_h[nxt][lane * 4];
                float d = wrow.x*hv.x + wrow.y*hv.y + wrow.z*hv.z + wrow.w*hv.w;
                #pragma unroll
                for (int off = 32; off > 0; off >>= 1) d += __shfl_down(d, off);
                if (lane == 0) whpn[(size_t)b * HR + p] = d + h2h_b[p];
            }
            __threadfence();
            grid.sync();
        }
    }

    // ---- final outputs ----
    if (g == 0) {
        o_v[(size_t)b * HH + tid]  = sh_v[tid];
        o_h[(size_t)b * HH + tid]  = sh_h[0][tid];
        o_te[(size_t)b * HH + tid] = sh_te[0][tid];
    }
    float4* o_dUv = (float4*)o_dU;
    float4* o_tEv = (float4*)o_tE;
    #pragma unroll
    for (int r = 0; r < 2; ++r) {
        const size_t rb = rbase + (size_t)r * (16 * 64);
        #pragma unroll
        for (int k = 0; k < 4; ++k) {
            o_dUv[rb + k * 16] = du[r][k];
            o_tEv[rb + k * 16] = tEr[r][k];
        }
    }
}

// ---------------- fallback per-step kernels (proven round-1 path) ----------
__global__ __launch_bounds__(HR) void k_step_a(
    const float* __restrict__ h_old, const float* __restrict__ v_old,
    const float* __restrict__ te_old, const float* __restrict__ Wx_t,
    const float* __restrict__ s_in,
    const float* __restrict__ h2h_w, const float* __restrict__ h2h_b,
    const float* __restrict__ lnh_g, const float* __restrict__ lnh_b,
    const float* __restrict__ sv, const float* __restrict__ mod2h,
    float* __restrict__ v_out, float* __restrict__ nh_out,
    float* __restrict__ nte_out, float* __restrict__ mod_out)
{
    __shared__ float hs[HH];
    __shared__ float modin[RR];
    __shared__ float rs[5], rs2[5];
    int b = blockIdx.x;
    int p = threadIdx.x;
    if (p < HH) hs[p] = h_old[(size_t)b * HH + p];
    __syncthreads();
    const float* wr = h2h_w + (size_t)p * HH;
    float acc = h2h_b[p];
    #pragma unroll 8
    for (int k = 0; k < HH; k += 4)
        acc += wr[k]*hs[k] + wr[k+1]*hs[k+1] + wr[k+2]*hs[k+2] + wr[k+3]*hs[k+3];
    float s = acc, s2 = acc * acc;
    int lane = p & 63, wv = p >> 6;
    for (int off = 32; off > 0; off >>= 1) { s += __shfl_down(s, off); s2 += __shfl_down(s2, off); }
    if (lane == 0) { rs[wv] = s; rs2[wv] = s2; }
    __syncthreads();
    float sum = 0.f, sum2 = 0.f;
    #pragma unroll
    for (int q = 0; q < 5; q++) { sum += rs[q]; sum2 += rs2[q]; }
    float mu = sum * (1.f / HR);
    float rstd = rsqrtf(sum2 * (1.f / HR) - mu * mu + 1e-5f);
    float wh = (acc - mu) * rstd * lnh_g[p] + lnh_b[p];
    float wx = Wx_t[(size_t)b * HR + p];
    if (p >= HH) {
        float m = wx + wh;
        modin[p - HH] = m > 0.f ? m : 0.f;
    } else {
        float dv = wx + wh + s_in[(size_t)b * HH + p];
        float svp = sv[p];
        float v = (1.f - svp) * v_old[(size_t)b * HH + p] + svp * dv;
        v_out[(size_t)b * HH + p] = v;
        float nh = v > 0.f ? v : 0.f;
        nh_out[(size_t)b * HH + p] = nh;
        nte_out[(size_t)b * HH + p] = (1.f - svp) * te_old[(size_t)b * HH + p] + svp * hs[p];
    }
    __syncthreads();
    if (p < HH) {
        const float* m2 = mod2h + (size_t)p * RR;
        float mm = 0.f;
        #pragma unroll 8
        for (int r = 0; r < RR; r += 4)
            mm += m2[r]*modin[r] + m2[r+1]*modin[r+1] + m2[r+2]*modin[r+2] + m2[r+3]*modin[r+3];
        mod_out[(size_t)b * HH + p] = mm;
    }
}

__global__ __launch_bounds__(256) void k_step_b(
    const float* __restrict__ dU_old, float* __restrict__ dU_new,
    const float* __restrict__ tE_old, float* __restrict__ tE_new,
    const float* __restrict__ nh, const float* __restrict__ h_old,
    const float* __restrict__ te_old, const float* __restrict__ nte,
    const float* __restrict__ mod,
    const float* __restrict__ ra, const float* __restrict__ sU,
    const float* __restrict__ sE, const float* __restrict__ hi,
    const float* __restrict__ lo,
    float* __restrict__ s_out)
{
    int r = blockIdx.x * 4 + (threadIdx.x >> 6);
    int lane = threadIdx.x & 63;
    int b = r >> 8, i = r & 255;
    size_t rowv = (size_t)r * 64 + lane;
    size_t cv   = (size_t)i * 64 + lane;
    size_t bv   = (size_t)b * 64 + lane;
    float4 du  = ((const float4*)dU_old)[rowv];
    float4 tE  = ((const float4*)tE_old)[rowv];
    float4 raV = ((const float4*)ra)[cv];
    float4 sUV = ((const float4*)sU)[cv];
    float4 sEV = ((const float4*)sE)[cv];
    float4 hiV = ((const float4*)hi)[cv];
    float4 loV = ((const float4*)lo)[cv];
    float4 teV = ((const float4*)te_old)[bv];
    float4 hV  = ((const float4*)h_old)[bv];
    float4 nhJ = ((const float4*)nh)[bv];
    float nhi  = nh[(size_t)b * HH + i];
    float ntei = nte[(size_t)b * HH + i];
    float modi = mod[(size_t)b * HH + i];

    float4 ntE, ndu;
    float acc = 0.f;
#define COMPONENT(c)                                                        \
    {                                                                       \
        float e = (1.f - sEV.c) * tE.c + sEV.c * (nhi * teV.c - ntei * hV.c); \
        float d = (1.f - sUV.c) * du.c + sUV.c * modi * e;                  \
        d = fminf(d, hiV.c); d = fmaxf(d, loV.c);                           \
        ntE.c = e; ndu.c = d;                                               \
        acc += raV.c * d * nhJ.c;                                           \
    }
    COMPONENT(x) COMPONENT(y) COMPONENT(z) COMPONENT(w)
#undef COMPONENT
    ((float4*)tE_new)[rowv] = ntE;
    ((float4*)dU_new)[rowv] = ndu;
    for (int off = 32; off > 0; off >>= 1) acc += __shfl_down(acc, off);
    if (lane == 0) s_out[r] = acc;
}

extern "C" void kernel_launch(void* const* d_in, const int* in_sizes, int n_in,
                              void* d_out, int out_size, void* d_ws, size_t ws_size,
                              hipStream_t stream)
{
    const float* x     = (const float*)d_in[0];
    const float* h0    = (const float*)d_in[1];
    const float* v0    = (const float*)d_in[2];
    const float* dU0   = (const float*)d_in[3];
    const float* te0   = (const float*)d_in[4];
    const float* tE0   = (const float*)d_in[5];
    const float* x2h_w = (const float*)d_in[6];
    const float* x2h_b = (const float*)d_in[7];
    const float* h2h_w = (const float*)d_in[8];
    const float* h2h_b = (const float*)d_in[9];
    const float* lnx_g = (const float*)d_in[10];
    const float* lnx_b = (const float*)d_in[11];
    const float* lnh_g = (const float*)d_in[12];
    const float* lnh_b = (const float*)d_in[13];
    const float* alpha = (const float*)d_in[14];
    const float* mod2h = (const float*)d_in[15];
    const float* tau_v = (const float*)d_in[16];
    const float* tau_U = (const float*)d_in[17];
    const float* tau_E = (const float*)d_in[18];

    float* out  = (float*)d_out;
    float* o_v  = out;
    float* o_h  = out + 16384;
    float* o_dU = out + 32768;
    float* o_te = out + 4227072;
    float* o_tE = out + 4243456;
    float* o_out= out + 8437760;

    float* w = (float*)d_ws;
    float* Wx    = w;  w += (size_t)T_STEPS * BB * HR;
    float* ra    = w;  w += HH * HH;
    float* sU    = w;  w += HH * HH;
    float* sE    = w;  w += HH * HH;
    float* hi    = w;  w += HH * HH;
    float* lo    = w;  w += HH * HH;
    float* sv    = w;  w += 256;
    float* sbufA = w;  w += BB * HH;
    float* sbufB = w;  w += BB * HH;
    float* whpA  = w;  w += BB * HR;
    float* whpB  = w;  w += BB * HR;
    float* modb  = w;  w += BB * HH;
    float* nteb0 = w;  w += BB * HH;
    float* nteb1 = w;  w += BB * HH;
    float* nteb[2] = { nteb0, nteb1 };

    k_init_const<<<256, 256, 0, stream>>>(alpha, tau_U, tau_E, tau_v, h2h_w,
                                          ra, sU, sE, hi, lo, sv);
    k_wx<<<T_STEPS * BB, HR, 0, stream>>>(x, x2h_w, x2h_b, lnx_g, lnx_b, Wx);
    k_s0<<<4096, 256, 0, stream>>>(dU0, h0, ra, sbufA);
    k_wh0<<<BB, HR, 0, stream>>>(h0, h2h_w, h2h_b, whpA);

    void* args[] = {
        (void*)&dU0, (void*)&tE0, (void*)&h0, (void*)&v0, (void*)&te0,
        (void*)&Wx, (void*)&h2h_w, (void*)&h2h_b, (void*)&lnh_g, (void*)&lnh_b,
        (void*)&sv, (void*)&mod2h,
        (void*)&ra, (void*)&sU, (void*)&sE, (void*)&hi, (void*)&lo,
        (void*)&whpA, (void*)&whpB, (void*)&sbufA, (void*)&sbufB,
        (void*)&o_v, (void*)&o_h, (void*)&o_dU, (void*)&o_te, (void*)&o_tE,
        (void*)&o_out
    };
    hipError_t cerr = hipLaunchCooperativeKernel((void*)k_scan, dim3(512),
                                                 dim3(256), args, 0, stream);
    if (cerr != hipSuccess) {
        // fallback: proven multi-kernel per-step path (uses sbufA as s_buf)
        for (int t = 0; t < T_STEPS; t++) {
            const float* h_old  = (t == 0) ? h0  : o_out + (size_t)(t - 1) * BB * HH;
            const float* v_old  = (t == 0) ? v0  : o_v;
            const float* te_oldp= (t == 0) ? te0 : nteb[(t + 1) & 1];
            const float* dUo    = (t == 0) ? dU0 : o_dU;
            const float* tEo    = (t == 0) ? tE0 : o_tE;
            float* nh = o_out + (size_t)t * BB * HH;
            k_step_a<<<BB, HR, 0, stream>>>(h_old, v_old, te_oldp,
                                            Wx + (size_t)t * BB * HR, sbufA,
                                            h2h_w, h2h_b, lnh_g, lnh_b, sv, mod2h,
                                            o_v, nh, nteb[t & 1], modb);
            k_step_b<<<4096, 256, 0, stream>>>(dUo, o_dU, tEo, o_tE, nh, h_old,
                                               te_oldp, nteb[t & 1], modb,
                                               ra, sU, sE, hi, lo, sbufA);
        }
        hipMemcpyAsync(o_h,  o_out + (size_t)(T_STEPS - 1) * BB * HH,
                       (size_t)BB * HH * 4, hipMemcpyDeviceToDevice, stream);
        hipMemcpyAsync(o_te, nteb[(T_STEPS - 1) & 1], (size_t)BB * HH * 4,
                       hipMemcpyDeviceToDevice, stream);
    }
}

// Round 7
// 1542.026 us; speedup vs baseline: 1.7177x; 1.7177x over previous
//
#include <hip/hip_runtime.h>

#define T_STEPS 24
#define BB 64
#define I_DIM 128
#define HH 256
#define RR 64
#define HR 320   // H + R
#define NREG_TE 7
#define NLDS_TE 9   // tE chunks 7..15 live in LDS

// ---------------- init: per-(i,j) constants, chunk-major swizzled ----------
// Element (i,j): c=j>>4, qq=(j>>2)&3, e=j&3. Owner thread t0=i*4+qq processes
// chunk c as float4 #(c*1024+t0). Swizzled flat index = (c*1024+i*4+qq)*4+e.
__global__ __launch_bounds__(256) void k_init_const(
    const float* __restrict__ alpha, const float* __restrict__ tau_U,
    const float* __restrict__ tau_E, const float* __restrict__ tau_v,
    const float* __restrict__ h2h_w,
    float* __restrict__ ra, float* __restrict__ sU, float* __restrict__ sE,
    float* __restrict__ hi, float* __restrict__ lo, float* __restrict__ sv)
{
    int idx = blockIdx.x * 256 + threadIdx.x;
    if (idx >= HH * HH) return;
    int i = idx >> 8, j = idx & 255;
    int c = j >> 4, qq = (j >> 2) & 3, e = j & 3;
    int sidx = (c * 1024 + i * 4 + qq) * 4 + e;
    float a = alpha[idx]; a = a > 0.f ? a : 0.f;
    ra[sidx] = a;
    sU[sidx] = 1.f / (1.f + expf(-tau_U[idx]));
    sE[sidx] = 1.f / (1.f + expf(-tau_E[idx]));
    float wv = h2h_w[idx];
    float inv = 1.f / (a + 1e-8f);
    float hi_ = 1.0f - wv; hi_ = hi_ > 0.f ? hi_ : 0.f;
    float lo_ = 1.0f + wv; lo_ = lo_ > 0.f ? lo_ : 0.f;
    hi[sidx] = hi_ * inv;
    lo[sidx] = -lo_ * inv;
    if (idx < HH) sv[idx] = 1.f / (1.f + expf(-tau_v[idx]));
}

// ---------------- init: Wx = LN(x @ x2h_w.T + b) for all T ----------------
__global__ __launch_bounds__(HR) void k_wx(
    const float* __restrict__ x, const float* __restrict__ w,
    const float* __restrict__ bias,
    const float* __restrict__ g, const float* __restrict__ be,
    float* __restrict__ Wx)
{
    __shared__ float xs[I_DIM];
    __shared__ float rs[5], rs2[5];
    int row = blockIdx.x;
    int p = threadIdx.x;
    if (p < I_DIM) xs[p] = x[(size_t)row * I_DIM + p];
    __syncthreads();
    const float* wr = w + (size_t)p * I_DIM;
    float acc = bias[p];
    #pragma unroll 8
    for (int k = 0; k < I_DIM; k += 4)
        acc += wr[k]*xs[k] + wr[k+1]*xs[k+1] + wr[k+2]*xs[k+2] + wr[k+3]*xs[k+3];
    float s = acc, s2 = acc * acc;
    int lane = p & 63, wv = p >> 6;
    for (int off = 32; off > 0; off >>= 1) { s += __shfl_down(s, off); s2 += __shfl_down(s2, off); }
    if (lane == 0) { rs[wv] = s; rs2[wv] = s2; }
    __syncthreads();
    float sum = 0.f, sum2 = 0.f;
    #pragma unroll
    for (int q = 0; q < 5; q++) { sum += rs[q]; sum2 += rs2[q]; }
    float mu = sum * (1.f / HR);
    float rstd = rsqrtf(sum2 * (1.f / HR) - mu * mu + 1e-5f);
    Wx[(size_t)row * HR + p] = (acc - mu) * rstd * g[p] + be[p];
}

// ---------------- persistent per-batch scan: 64 blocks x 1024 threads ------
// Thread t0: row i=t0>>2, qq=t0&3; owns j = c*16+qq*4+{0..3}, c=0..15.
// dU: 16 f4 chunks in regs. tE: chunks 0..6 regs, 7..15 in LDS.
// Only __syncthreads() — no cross-block communication at all.
__global__ __launch_bounds__(1024) void k_batch(
    const float* __restrict__ dU0, const float* __restrict__ tE0,
    const float* __restrict__ h0, const float* __restrict__ v0,
    const float* __restrict__ te0,
    const float* __restrict__ Wx,      // (T,B,HR)
    const float* __restrict__ h2h_w, const float* __restrict__ h2h_b,
    const float* __restrict__ lnh_g, const float* __restrict__ lnh_b,
    const float* __restrict__ sv_g,
    const float* __restrict__ mod2h,   // (H,R) natural layout
    const float* __restrict__ raS, const float* __restrict__ sUS,
    const float* __restrict__ sES, const float* __restrict__ hiS,
    const float* __restrict__ loS,     // swizzled chunk-major
    float* __restrict__ o_v, float* __restrict__ o_h, float* __restrict__ o_dU,
    float* __restrict__ o_te, float* __restrict__ o_tE, float* __restrict__ o_out)
{
    __shared__ __align__(16) float4 tE_lds[NLDS_TE * 1024];   // 147456 B
    __shared__ __align__(16) float sh_h[2][HH];
    __shared__ __align__(16) float sh_te[2][HH];
    __shared__ float sh_v[HH];
    __shared__ float sh_s[HH];
    __shared__ __align__(16) float sh_modin[RR];
    __shared__ float sh_red[5], sh_red2[5];

    const int b   = blockIdx.x;
    const int t0  = threadIdx.x;
    const int i   = t0 >> 2;
    const int qq  = t0 & 3;
    const int wv  = t0 >> 6;
    const int lane = t0 & 63;

    // hoisted per-thread constants (phase A roles)
    float g0 = 0.f, be0 = 0.f, hb = 0.f, svp = 0.f;
    const float4* wr4 = (const float4*)h2h_w;
    if (t0 < HR) {
        g0 = lnh_g[t0]; be0 = lnh_b[t0]; hb = h2h_b[t0];
        wr4 = (const float4*)(h2h_w + (size_t)t0 * HH);
        if (t0 < HH) svp = sv_g[t0];
    }

    const float4* raS4 = (const float4*)raS;
    const float4* sUS4 = (const float4*)sUS;
    const float4* sES4 = (const float4*)sES;
    const float4* hiS4 = (const float4*)hiS;
    const float4* loS4 = (const float4*)loS;
    const float4* m2h4 = (const float4*)mod2h;

    // ---- load persistent state ----
    const size_t sbase = ((size_t)b * HH + i) * 64 + qq;   // f4 units; chunk c at +c*4
    const float4* dU0v = (const float4*)dU0;
    const float4* tE0v = (const float4*)tE0;
    float4 duR[16];
    float4 teR[NREG_TE];
    #pragma unroll
    for (int c = 0; c < 16; ++c) duR[c] = dU0v[sbase + c * 4];
    #pragma unroll
    for (int c = 0; c < NREG_TE; ++c) teR[c] = tE0v[sbase + c * 4];
    #pragma unroll
    for (int c2 = 0; c2 < NLDS_TE; ++c2)
        tE_lds[c2 * 1024 + t0] = tE0v[sbase + (NREG_TE + c2) * 4];

    if (t0 < HH) {
        sh_h[0][t0]  = h0[(size_t)b * HH + t0];
        sh_te[0][t0] = te0[(size_t)b * HH + t0];
        sh_v[t0]     = v0[(size_t)b * HH + t0];
    }
    __syncthreads();

    // ---- initial s = einsum(ra*dU0, h0) ----
    {
        float acc = 0.f;
        #pragma unroll
        for (int c = 0; c < 16; ++c) {
            const float4 raV = raS4[c * 1024 + t0];
            const int j0 = c * 16 + qq * 4;
            const float4 h4 = *(const float4*)&sh_h[0][j0];
            const float4 d = duR[c];
            acc += raV.x*d.x*h4.x + raV.y*d.y*h4.y + raV.z*d.z*h4.z + raV.w*d.w*h4.w;
        }
        acc += __shfl_xor(acc, 1, 4);
        acc += __shfl_xor(acc, 2, 4);
        if (qq == 0) sh_s[i] = acc;
    }
    __syncthreads();

    #pragma unroll 1
    for (int t = 0; t < T_STEPS; ++t) {
        const int cur = t & 1, nxt = cur ^ 1;

        // ---- A1: Wh_pre matvec (threads 0..319, one row each) ----
        float pre = 0.f;
        if (t0 < HR) {
            float a0 = hb, a1 = 0.f;
            #pragma unroll 8
            for (int k = 0; k < 64; k += 2) {
                float4 w0 = wr4[k],     w1 = wr4[k+1];
                float4 h0v = *(const float4*)&sh_h[cur][k << 2];
                float4 h1v = *(const float4*)&sh_h[cur][(k+1) << 2];
                a0 += w0.x*h0v.x + w0.y*h0v.y + w0.z*h0v.z + w0.w*h0v.w;
                a1 += w1.x*h1v.x + w1.y*h1v.y + w1.z*h1v.z + w1.w*h1v.w;
            }
            pre = a0 + a1;
            float s = pre, s2 = pre * pre;
            #pragma unroll
            for (int off = 32; off > 0; off >>= 1) {
                s += __shfl_down(s, off); s2 += __shfl_down(s2, off);
            }
            if (lane == 0) { sh_red[wv] = s; sh_red2[wv] = s2; }
        }
        __syncthreads();

        // ---- A2: LN + v/nh/nte/modin ----
        {
            float sum = 0.f, sum2 = 0.f;
            #pragma unroll
            for (int q = 0; q < 5; ++q) { sum += sh_red[q]; sum2 += sh_red2[q]; }
            float mu = sum * (1.f / HR);
            float rstd = rsqrtf(sum2 * (1.f / HR) - mu * mu + 1e-5f);
            if (t0 < HR) {
                float wh = (pre - mu) * rstd * g0 + be0;
                float wx = Wx[((size_t)t * BB + b) * HR + t0];
                if (t0 < HH) {
                    float dv = wx + wh + sh_s[t0];
                    float vnew = (1.f - svp) * sh_v[t0] + svp * dv;
                    sh_v[t0] = vnew;
                    float nh = vnew > 0.f ? vnew : 0.f;
                    sh_h[nxt][t0] = nh;
                    sh_te[nxt][t0] = (1.f - svp) * sh_te[cur][t0] + svp * sh_h[cur][t0];
                    o_out[((size_t)t * BB + b) * HH + t0] = nh;
                } else {
                    float m = wx + wh;
                    sh_modin[t0 - HH] = m > 0.f ? m : 0.f;
                }
            }
        }
        __syncthreads();

        // ---- B: mod_i + dU/tE register update + fused einsum ----
        {
            float macc = 0.f;
            #pragma unroll
            for (int e = 0; e < 4; ++e) {
                const float4 m4 = m2h4[i * 16 + qq * 4 + e];
                const float4 mi = *(const float4*)&sh_modin[qq * 16 + e * 4];
                macc += m4.x*mi.x + m4.y*mi.y + m4.z*mi.z + m4.w*mi.w;
            }
            macc += __shfl_xor(macc, 1, 4);
            macc += __shfl_xor(macc, 2, 4);
            const float modi = macc;
            const float nhi  = sh_h[nxt][i];
            const float ntei = sh_te[nxt][i];
            float acc = 0.f;

#define UPDC(cc, TE) { \
            const float4 raV = raS4[(cc) * 1024 + t0]; \
            const float4 sUV = sUS4[(cc) * 1024 + t0]; \
            const float4 sEV = sES4[(cc) * 1024 + t0]; \
            const float4 hiV = hiS4[(cc) * 1024 + t0]; \
            const float4 loV = loS4[(cc) * 1024 + t0]; \
            const int j0 = (cc) * 16 + qq * 4; \
            const float4 teo = *(const float4*)&sh_te[cur][j0]; \
            const float4 ho  = *(const float4*)&sh_h[cur][j0]; \
            const float4 hn  = *(const float4*)&sh_h[nxt][j0]; \
            float4 DU = duR[cc]; \
            { float ev = (1.f-sEV.x)*TE.x + sEV.x*(nhi*teo.x - ntei*ho.x); \
              float dd = (1.f-sUV.x)*DU.x + sUV.x*modi*ev; \
              dd = fminf(dd, hiV.x); dd = fmaxf(dd, loV.x); \
              TE.x = ev; DU.x = dd; acc += raV.x*dd*hn.x; } \
            { float ev = (1.f-sEV.y)*TE.y + sEV.y*(nhi*teo.y - ntei*ho.y); \
              float dd = (1.f-sUV.y)*DU.y + sUV.y*modi*ev; \
              dd = fminf(dd, hiV.y); dd = fmaxf(dd, loV.y); \
              TE.y = ev; DU.y = dd; acc += raV.y*dd*hn.y; } \
            { float ev = (1.f-sEV.z)*TE.z + sEV.z*(nhi*teo.z - ntei*ho.z); \
              float dd = (1.f-sUV.z)*DU.z + sUV.z*modi*ev; \
              dd = fminf(dd, hiV.z); dd = fmaxf(dd, loV.z); \
              TE.z = ev; DU.z = dd; acc += raV.z*dd*hn.z; } \
            { float ev = (1.f-sEV.w)*TE.w + sEV.w*(nhi*teo.w - ntei*ho.w); \
              float dd = (1.f-sUV.w)*DU.w + sUV.w*modi*ev; \
              dd = fminf(dd, hiV.w); dd = fmaxf(dd, loV.w); \
              TE.w = ev; DU.w = dd; acc += raV.w*dd*hn.w; } \
            duR[cc] = DU; }

            #pragma unroll
            for (int c = 0; c < NREG_TE; ++c) { UPDC(c, teR[c]); }
            #pragma unroll
            for (int c2 = 0; c2 < NLDS_TE; ++c2) {
                float4 TE = tE_lds[c2 * 1024 + t0];
                UPDC(NREG_TE + c2, TE);
                tE_lds[c2 * 1024 + t0] = TE;
            }
#undef UPDC

            acc += __shfl_xor(acc, 1, 4);
            acc += __shfl_xor(acc, 2, 4);
            if (qq == 0) sh_s[i] = acc;
        }
        // no sync here: next A1 only reads sh_h[nxt] (stable) and writes
        // sh_red, whose readers (A2) are behind the A1->A2 sync.
    }

    __syncthreads();
    // ---- final outputs: T even -> final h/te in parity 0 ----
    if (t0 < HH) {
        o_v[(size_t)b * HH + t0]  = sh_v[t0];
        o_h[(size_t)b * HH + t0]  = sh_h[0][t0];
        o_te[(size_t)b * HH + t0] = sh_te[0][t0];
    }
    float4* o_dUv = (float4*)o_dU;
    float4* o_tEv = (float4*)o_tE;
    #pragma unroll
    for (int c = 0; c < 16; ++c) o_dUv[sbase + c * 4] = duR[c];
    #pragma unroll
    for (int c = 0; c < NREG_TE; ++c) o_tEv[sbase + c * 4] = teR[c];
    #pragma unroll
    for (int c2 = 0; c2 < NLDS_TE; ++c2)
        o_tEv[sbase + (NREG_TE + c2) * 4] = tE_lds[c2 * 1024 + t0];
}

extern "C" void kernel_launch(void* const* d_in, const int* in_sizes, int n_in,
                              void* d_out, int out_size, void* d_ws, size_t ws_size,
                              hipStream_t stream)
{
    const float* x     = (const float*)d_in[0];
    const float* h0    = (const float*)d_in[1];
    const float* v0    = (const float*)d_in[2];
    const float* dU0   = (const float*)d_in[3];
    const float* te0   = (const float*)d_in[4];
    const float* tE0   = (const float*)d_in[5];
    const float* x2h_w = (const float*)d_in[6];
    const float* x2h_b = (const float*)d_in[7];
    const float* h2h_w = (const float*)d_in[8];
    const float* h2h_b = (const float*)d_in[9];
    const float* lnx_g = (const float*)d_in[10];
    const float* lnx_b = (const float*)d_in[11];
    const float* lnh_g = (const float*)d_in[12];
    const float* lnh_b = (const float*)d_in[13];
    const float* alpha = (const float*)d_in[14];
    const float* mod2h = (const float*)d_in[15];
    const float* tau_v = (const float*)d_in[16];
    const float* tau_U = (const float*)d_in[17];
    const float* tau_E = (const float*)d_in[18];

    float* out  = (float*)d_out;
    float* o_v  = out;
    float* o_h  = out + 16384;
    float* o_dU = out + 32768;
    float* o_te = out + 4227072;
    float* o_tE = out + 4243456;
    float* o_out= out + 8437760;

    float* w = (float*)d_ws;
    float* Wx  = w;  w += (size_t)T_STEPS * BB * HR;
    float* ra  = w;  w += HH * HH;
    float* sU  = w;  w += HH * HH;
    float* sE  = w;  w += HH * HH;
    float* hi  = w;  w += HH * HH;
    float* lo  = w;  w += HH * HH;
    float* sv  = w;  w += 256;

    k_init_const<<<256, 256, 0, stream>>>(alpha, tau_U, tau_E, tau_v, h2h_w,
                                          ra, sU, sE, hi, lo, sv);
    k_wx<<<T_STEPS * BB, HR, 0, stream>>>(x, x2h_w, x2h_b, lnx_g, lnx_b, Wx);
    k_batch<<<BB, 1024, 0, stream>>>(dU0, tE0, h0, v0, te0, Wx,
                                     h2h_w, h2h_b, lnh_g, lnh_b, sv, mod2h,
                                     ra, sU, sE, hi, lo,
                                     o_v, o_h, o_dU, o_te, o_tE, o_out);
}